// Round 10
// baseline (1391.994 us; speedup 1.0000x reference)
//
#include <hip/hip_runtime.h>
#include <cstdint>
#include <cstddef>

#define HW    1444      // 38*38
#define NA    12996     // HW*9
#define NPRE  3000
#define NW    47        // ceil(3000/64)
#define NPOST 300

// d_out section offsets (in floats)
#define OFF_LOCS   0         // 4*12996*4 = 207936
#define OFF_SCORES 207936    // 4*12996*2 = 103968
#define OFF_ROIS   311904    // 1200*4    = 4800
#define OFF_IDX    316704    // 4*300     = 1200
#define OFF_ANCH   317904    // 12996*4   = 51984

#define INVALID_KEY 0xFFF0000000000000ULL

typedef float f32x2 __attribute__((ext_vector_type(2)));
typedef float f32x4 __attribute__((ext_vector_type(4)));

__device__ inline double as_dim(int raw) {
  if (raw > 0 && raw < 1000000) return (double)raw;
  return (double)__int_as_float(raw);
}

// ---------------- W transpose: Wt[c*64 + o], o<36 loc, 36..53 score ----------
__global__ __launch_bounds__(256) void wt_k(const float* __restrict__ lw,
                                            const float* __restrict__ sw,
                                            float* __restrict__ Wt) {
  int t = blockIdx.x * 256 + threadIdx.x;
  if (t >= 64 * 512) return;
  int o = t & 63, c = t >> 6;
  float v = 0.f;
  if (o < 36)      v = lw[o * 512 + c];
  else if (o < 54) v = sw[(o - 36) * 512 + c];
  Wt[t] = v;
}

// ------- 3x3 conv: w global->VGPR (late-issue prefetch), x b128 LDS ---------
// R10 (R9 post-mortem: still LDS-issue-bound; 59 ds-ops/wave-cc, w path = 18
// of them). R8 proved global w is CORRECT but stalled at prefetch distance 0;
// here wq[9] (f32x4, single-buffered VGPR) loads for cc+1 are issued right
// AFTER the last use of wq (cl=3 wp-extraction) -> ~300+cy of pk_fma + fold
// + barriers + x-staging covers L2 latency (W o-panel is L2-hot: 1.2 MB read
// by 152 blocks). ds-ops/wave-cc: 59 -> 41. LDS 13.3 -> 4 KB.
// x dual-copy b128 path + staging + pk_fma order VERBATIM R9 -> feat
// BIT-IDENTICAL -> selection untouched.
__global__ __launch_bounds__(256) void conv_k(const float* __restrict__ X,
                                              const float* __restrict__ W,
                                              const float* __restrict__ B,
                                              float* __restrict__ F) {
  __shared__ float Xs[1008];   // A: [4cl][3row][40]=480 | B: [4cl][3row][44]=528
  const int tid  = threadIdx.x;
  const int lane = tid & 63;
  const int wv   = tid >> 6;
  const int seg  = wv * 10;        // cols seg..seg+9 (wave 3: 30..37 + 2 dummy)
  const int y  = blockIdx.x;
  const int o0 = blockIdx.y * 64;
  const int n  = blockIdx.z;
  const float* xn = X + ((size_t)n * 512) * HW;
  const float* Wl = W + (size_t)(o0 + lane) * 4608;   // this lane's o-row

  // ---- staging descriptors (computed once) ----
  // copy A: e -> cl=e/120, row=(e%120)/40, colA=e%40, imgcol m=colA-1
  int xsrcA[2]; bool xvalA[2]; bool xactA1;
  {
    int e = tid;
    int cl = e / 120, rem = e - cl * 120, row = rem / 40, colA = rem - row * 40;
    int m = colA - 1, iy = y - 1 + row;
    xvalA[0] = (m >= 0 && m < 38 && iy >= 0 && iy < 38);
    xsrcA[0] = xvalA[0] ? (cl * HW + iy * 38 + m) : 0;
  }
  {
    int e = tid + 256; xactA1 = (e < 480);
    int cl = e / 120, rem = e - cl * 120, row = rem / 40, colA = rem - row * 40;
    int m = colA - 1, iy = y - 1 + row;
    xvalA[1] = xactA1 && (m >= 0 && m < 38 && iy >= 0 && iy < 38);
    xsrcA[1] = xvalA[1] ? (cl * HW + iy * 38 + m) : 0;
  }
  // copy B: e -> cl=e/132, row=(e%132)/44, colB=e%44, imgcol m=colB-3
  int xsrcB[3]; bool xvalB[3]; bool xactB2;
#pragma unroll
  for (int u = 0; u < 3; ++u) {
    int e = tid + u * 256;
    bool act = (e < 528);
    int cl = e / 132, rem = e - cl * 132, row = rem / 44, colB = rem - row * 44;
    int m = colB - 3, iy = y - 1 + row;
    xvalB[u] = act && (m >= 0 && m < 38 && iy >= 0 && iy < 38);
    xsrcB[u] = xvalB[u] ? (cl * HW + iy * 38 + m) : 0;
    if (u == 2) xactB2 = act;
  }

  float xrA[2], xrB[3];
#pragma unroll
  for (int u = 0; u < 2; ++u) xrA[u] = xvalA[u] ? xn[xsrcA[u]] : 0.f;
#pragma unroll
  for (int u = 0; u < 3; ++u) xrB[u] = xvalB[u] ? xn[xsrcB[u]] : 0.f;

  // prologue: weights for cc=0
  f32x4 wq[9];
  {
    const f32x4* wp4 = (const f32x4*)Wl;
#pragma unroll
    for (int q = 0; q < 9; ++q) wq[q] = wp4[q];
  }

  double acc[10];
#pragma unroll
  for (int p = 0; p < 10; ++p) acc[p] = 0.;
  f32x2 pA[5], pB[5];
  float pc0 = 0.f;

  const int  xb0   = (wv & 1) ? (480 + seg + 2) : seg;
  const int  cstep = (wv & 1) ? 132 : 120;
  const int  kstep = (wv & 1) ? 44 : 40;

#define WQ_ELEM(t) ((t & 3) == 0 ? wq[(t) >> 2].x : (t & 3) == 1 ? wq[(t) >> 2].y : \
                    (t & 3) == 2 ? wq[(t) >> 2].z : wq[(t) >> 2].w)

  for (int cc = 0; cc < 128; ++cc) {
    __syncthreads();
    Xs[tid] = xrA[0];
    if (xactA1) Xs[tid + 256] = xrA[1];
    Xs[480 + tid] = xrB[0];
    Xs[480 + tid + 256] = xrB[1];
    if (xactB2) Xs[480 + tid + 512] = xrB[2];
    __syncthreads();
    // x prefetch for cc+1 (in flight during compute; R7/R9-proven pattern)
    if (cc < 127) {
      const int cb = (cc + 1) * 4;
#pragma unroll
      for (int u = 0; u < 2; ++u) xrA[u] = xvalA[u] ? xn[cb * HW + xsrcA[u]] : 0.f;
#pragma unroll
      for (int u = 0; u < 3; ++u) xrB[u] = xvalB[u] ? xn[cb * HW + xsrcB[u]] : 0.f;
    }
    if ((cc & 1) == 0) {
#pragma unroll
      for (int a = 0; a < 5; ++a) { pA[a] = (f32x2)(0.f); pB[a] = (f32x2)(0.f); }
      pc0 = 0.f;
    }
#pragma unroll
    for (int cl = 0; cl < 4; ++cl) {
      f32x2 wp[9];
#pragma unroll
      for (int k = 0; k < 9; ++k) {
        float wv0 = WQ_ELEM(cl * 9 + k);
        wp[k][0] = wv0; wp[k][1] = wv0;
      }
      // after the LAST use of wq (cl=3 extraction): issue loads for cc+1.
      // distance to first use next cc: 45 pk_fma + fold + 2 barriers +
      // x-staging -> L2 latency hidden (R8's distance-0 mistake fixed).
      if (cl == 3 && cc < 127) {
        const f32x4* wn = (const f32x4*)(Wl + (cc + 1) * 36);
#pragma unroll
        for (int q = 0; q < 9; ++q) wq[q] = wn[q];
      }
#pragma unroll
      for (int ky = 0; ky < 3; ++ky) {
        const float* xrow = &Xs[xb0 + cl * cstep + ky * kstep]; // 16B-aligned
        f32x4 q0 = *(const f32x4*)(xrow);
        f32x4 q1 = *(const f32x4*)(xrow + 4);
        f32x4 q2 = *(const f32x4*)(xrow + 8);
        f32x2 xp[6];
        xp[0] = __builtin_shufflevector(q0, q0, 0, 1);
        xp[1] = __builtin_shufflevector(q0, q0, 2, 3);
        xp[2] = __builtin_shufflevector(q1, q1, 0, 1);
        xp[3] = __builtin_shufflevector(q1, q1, 2, 3);
        xp[4] = __builtin_shufflevector(q2, q2, 0, 1);
        xp[5] = __builtin_shufflevector(q2, q2, 2, 3);
        // kx=0 -> pA: cols (2a,2a+1) += w0 * (x[2a],x[2a+1])
#pragma unroll
        for (int a = 0; a < 5; ++a)
          asm("v_pk_fma_f32 %0, %1, %2, %0"
              : "+v"(pA[a]) : "v"(xp[a]), "v"(wp[ky * 3 + 0]));
        // kx=1 -> pB: cols (2a+1,2a+2) += w1 * (x[2a+2],x[2a+3]); col0 scalar
        pc0 = fmaf(wp[ky * 3 + 1][0], xp[0][1], pc0);
#pragma unroll
        for (int a = 0; a < 5; ++a)
          asm("v_pk_fma_f32 %0, %1, %2, %0"
              : "+v"(pB[a]) : "v"(xp[a + 1]), "v"(wp[ky * 3 + 1]));
        // kx=2 -> pA: cols (2a,2a+1) += w2 * (x[2a+2],x[2a+3])
#pragma unroll
        for (int a = 0; a < 5; ++a)
          asm("v_pk_fma_f32 %0, %1, %2, %0"
              : "+v"(pA[a]) : "v"(xp[a + 1]), "v"(wp[ky * 3 + 2]));
      }
    }
    if (cc & 1) {
      acc[0] += (double)(pA[0][0] + pc0);
#pragma unroll
      for (int p = 1; p < 10; ++p) {
        float sa = pA[p >> 1][p & 1];
        float sb = (p & 1) ? pB[(p - 1) >> 1][0] : pB[(p - 2) >> 1][1];
        acc[p] += (double)(sa + sb);
      }
    }
  }
  double bb = (double)B[o0 + lane];
  float* fp = F + ((size_t)(n * 512 + o0 + lane)) * HW + y * 38;
#pragma unroll
  for (int p = 0; p < 10; ++p) {
    int col = seg + p;
    if (col < 38) fp[col] = (float)fmax(acc[p] + bb, 0.0);
  }
}

// ------- 1x1 heads (fp64) + bias + layout transform + fp64 softmax fg -------
__global__ __launch_bounds__(256) void heads_k(const float* __restrict__ F,
                                               const float* __restrict__ Wt,
                                               const float* __restrict__ lb,
                                               const float* __restrict__ sb,
                                               float* __restrict__ out,
                                               double* __restrict__ fg) {
  __shared__ float sf[512 * 4];
  __shared__ double ssc[4][18];
  int n = blockIdx.y;
  int p0 = blockIdx.x * 4;
  int tid = threadIdx.x;
  const float* fn = F + ((size_t)n * 512) * HW;
  for (int e = tid; e < 2048; e += 256) {
    int c = e >> 2, pl = e & 3;
    sf[e] = fn[c * HW + p0 + pl];
  }
  __syncthreads();
  int pl = tid & 3, o = tid >> 2;
  double acc = 0.;
  if (o < 54) {
    for (int c = 0; c < 512; ++c)
      acc = fma((double)Wt[(c << 6) | o], (double)sf[(c << 2) | pl], acc);
  }
  int p = p0 + pl;
  if (o < 36) {
    acc += (double)lb[o];
    out[OFF_LOCS + ((size_t)n * NA + (size_t)p * 9 + (o >> 2)) * 4 + (o & 3)] = (float)acc;
  } else if (o < 54) {
    int oo = o - 36;
    acc += (double)sb[oo];
    out[OFF_SCORES + ((size_t)n * NA + (size_t)p * 9 + (oo >> 1)) * 2 + (oo & 1)] = (float)acc;
    ssc[pl][oo] = acc;
  }
  __syncthreads();
  if (tid < 36) {
    int pl2 = tid / 9, a = tid - pl2 * 9;
    double s0 = ssc[pl2][a * 2], s1 = ssc[pl2][a * 2 + 1];
    double mx = fmax(s0, s1);
    double e0 = exp(s0 - mx), e1 = exp(s1 - mx);
    fg[(size_t)n * NA + (size_t)(p0 + pl2) * 9 + a] = e1 / (e0 + e1);
  }
}

// ------ decode boxes (fp64) + inline anchors + valid + sort keys ------------
__global__ __launch_bounds__(256) void decode_k(const float* __restrict__ out_c,
                                                float* __restrict__ out,
                                                const double* __restrict__ fg,
                                                const int* __restrict__ ihp,
                                                const int* __restrict__ iwp,
                                                double* __restrict__ boxes,
                                                unsigned long long* __restrict__ keys) {
  int t = blockIdx.x * 256 + threadIdx.x;   // 4*16384 exactly
  int n = t >> 14, i = t & 16383;
  if (i >= NA) { keys[t] = ~0ULL; return; }
  int p = i / 9, a = i - p * 9;
  int ri = a / 3, si = a - ri * 3;
  double sr  = (ri == 0) ? 0.7071067811865476 : (ri == 1 ? 1.0 : 1.4142135623730951);
  double sri = (ri == 0) ? 1.4142135623730951 : (ri == 1 ? 1.0 : 0.7071067811865476);
  double hs = (double)(128 << si) * sr;
  double wd = (double)(128 << si) * sri;
  int py = p / 38, px = p - py * 38;
  float sx = (float)(px * 16), sy = (float)(py * 16);
  float fx1 = (float)(8.0 - 0.5 * wd), fy1 = (float)(8.0 - 0.5 * hs);
  float fx2 = (float)(8.0 + 0.5 * wd), fy2 = (float)(8.0 + 0.5 * hs);
  float ax1f = sx + fx1, ay1f = sy + fy1, ax2f = sx + fx2, ay2f = sy + fy2;
  if (n == 0) {
    float* ap = out + OFF_ANCH + (size_t)i * 4;
    ap[0] = ax1f; ap[1] = ay1f; ap[2] = ax2f; ap[3] = ay2f;
  }
  double ax1 = ax1f, ay1 = ay1f, ax2 = ax2f, ay2 = ay2f;
  double aw = ax2 - ax1, ah = ay2 - ay1;
  double acx = ax1 + 0.5 * aw, acy = ay1 + 0.5 * ah;
  const float* lp = out_c + OFF_LOCS + ((size_t)n * NA + i) * 4;
  double cx = (double)lp[0] * aw + acx, cy = (double)lp[1] * ah + acy;
  double bw = aw * exp((double)lp[2]), bh = ah * exp((double)lp[3]);
  double iwf = as_dim(iwp[0]), ihf = as_dim(ihp[0]);
  double x1 = fmin(fmax(cx - 0.5 * bw, 0.0), iwf);
  double y1 = fmin(fmax(cy - 0.5 * bh, 0.0), ihf);
  double x2 = fmin(fmax(cx + 0.5 * bw, 0.0), iwf);
  double y2 = fmin(fmax(cy + 0.5 * bh, 0.0), ihf);
  bool valid = ((x2 - x1) >= 16.0) && ((y2 - y1) >= 16.0);
  double* bp = boxes + ((size_t)n * NA + i) * 4;
  bp[0] = x1; bp[1] = y1; bp[2] = x2; bp[3] = y2;
  double sc = fg[(size_t)n * NA + i];
  unsigned long long u = (unsigned long long)__double_as_longlong(sc);
  u = (u >> 63) ? ~u : (u | 0x8000000000000000ULL);  // ascending-sortable
  unsigned long long inv = ~u;                       // descending
  if (!valid) inv = INVALID_KEY;
  keys[t] = (inv & ~0x3FFFULL) | (unsigned long long)i;  // 50-bit score + idx
}

// ---- sort phase A: per-8192-half in-LDS bitonic sort (half0 asc, half1 desc)
__global__ __launch_bounds__(1024) void sortA_k(unsigned long long* __restrict__ keys) {
  __shared__ unsigned long long s[8192];   // 64 KB
  const int half = blockIdx.x & 1;
  unsigned long long* g = keys + (((size_t)(blockIdx.x >> 1)) << 14) + ((size_t)half << 13);
  const int tid = threadIdx.x;
  for (int i = tid; i < 8192; i += 1024) s[i] = g[i];
  for (int size = 2; size <= 8192; size <<= 1) {
    for (int stride = size >> 1; stride > 0; stride >>= 1) {
      __syncthreads();
      for (int u = tid; u < 4096; u += 1024) {
        int lo = u & (stride - 1);
        int i1 = ((u - lo) << 1) | lo;
        int i2 = i1 + stride;
        bool up = (i1 & size) == 0;
        if (half) up = !up;   // upper half sorts descending
        unsigned long long a = s[i1], b = s[i2];
        if ((a > b) == up) { s[i1] = b; s[i2] = a; }
      }
    }
  }
  __syncthreads();
  for (int i = tid; i < 8192; i += 1024) g[i] = s[i];
}

// ---- sort phase B: single global stride-8192 compare-exchange (ascending) --
__global__ __launch_bounds__(256) void sortB_k(unsigned long long* __restrict__ keys) {
  int t = blockIdx.x * 256 + threadIdx.x;   // 4*8192
  int n = t >> 13, i = t & 8191;
  unsigned long long* g = keys + ((size_t)n << 14);
  unsigned long long a = g[i], b = g[i + 8192];
  if (a > b) { g[i] = b; g[i + 8192] = a; }
}

// ---- sort phase C: per-8192-half in-LDS bitonic merge (ascending) ----------
__global__ __launch_bounds__(1024) void sortC_k(unsigned long long* __restrict__ keys) {
  __shared__ unsigned long long s[8192];
  unsigned long long* g = keys + (((size_t)(blockIdx.x >> 1)) << 14) + ((size_t)(blockIdx.x & 1) << 13);
  const int tid = threadIdx.x;
  for (int i = tid; i < 8192; i += 1024) s[i] = g[i];
  for (int stride = 4096; stride > 0; stride >>= 1) {
    __syncthreads();
    for (int u = tid; u < 4096; u += 1024) {
      int lo = u & (stride - 1);
      int i1 = ((u - lo) << 1) | lo;
      int i2 = i1 + stride;
      unsigned long long a = s[i1], b = s[i2];
      if (a > b) { s[i1] = b; s[i2] = a; }
    }
  }
  __syncthreads();
  for (int i = tid; i < 8192; i += 1024) g[i] = s[i];
}

// ---------------- gather sorted top-3000 boxes + valid bit-words ------------
__global__ void gather_k(const unsigned long long* __restrict__ keys,
                         const double* __restrict__ boxes,
                         double* __restrict__ bsort,
                         unsigned long long* __restrict__ vw) {
  int n = blockIdx.y, w = blockIdx.x, l = threadIdx.x;  // 47 x 4 blocks, 64 thr
  int r = w * 64 + l;
  bool valid = false;
  if (r < NPRE) {
    unsigned long long kk = keys[((size_t)n << 14) + r];
    valid = kk < INVALID_KEY;
    unsigned idx = (unsigned)(kk & 0x3FFFULL);
    const double* bp = boxes + ((size_t)n * NA + idx) * 4;
    double* dp = bsort + ((size_t)n * NPRE + r) * 4;
    dp[0] = bp[0]; dp[1] = bp[1]; dp[2] = bp[2]; dp[3] = bp[3];
  }
  unsigned long long mask = __ballot(valid);
  if (l == 0) vw[n * NW + w] = mask;
}

// ------- suppression matrix (fp64 IoU): bit j set iff j>i && iou>0.7 --------
__global__ __launch_bounds__(256) void iou_k(const double* __restrict__ bsort,
                                             unsigned long long* __restrict__ sup) {
  int t = blockIdx.x * 256 + threadIdx.x;
  if (t >= 4 * NPRE * NW) return;
  int w = t % NW; int rest = t / NW; int i = rest % NPRE; int n = rest / NPRE;
  const double* bb = bsort + (size_t)n * NPRE * 4;
  double bix1 = bb[(size_t)i*4], biy1 = bb[(size_t)i*4+1];
  double bix2 = bb[(size_t)i*4+2], biy2 = bb[(size_t)i*4+3];
  double ai = (bix2 - bix1) * (biy2 - biy1);
  unsigned long long word = 0ULL;
  int j0 = w << 6;
  if (j0 + 63 > i) {
    int lmax = NPRE - j0; if (lmax > 64) lmax = 64;
    for (int l = 0; l < lmax; ++l) {
      int j = j0 + l;
      if (j <= i) continue;
      const double* bj = bb + (size_t)j * 4;
      double aj = (bj[2] - bj[0]) * (bj[3] - bj[1]);
      double xx1 = fmax(bix1, bj[0]), yy1 = fmax(biy1, bj[1]);
      double xx2 = fmin(bix2, bj[2]), yy2 = fmin(biy2, bj[3]);
      double inter = fmax(xx2 - xx1, 0.0) * fmax(yy2 - yy1, 0.0);
      double uni = ai + aj - inter;
      double iou = (uni > 0.0) ? inter / uni : 0.0;
      word |= (unsigned long long)(iou > 0.7) << l;
    }
  }
  sup[((size_t)n * NPRE + i) * NW + w] = word;
}

// ------- NMS: block-64 mask propagation (1 wave/batch) + emit rois ----------
// propagation loads batched 8-wide into independent registers; keep set &
// order unchanged -> outputs identical.
__global__ void nms_k(const unsigned long long* __restrict__ sup,
                      const unsigned long long* __restrict__ vwp,
                      const double* __restrict__ bsort,
                      float* __restrict__ out) {
  int n = blockIdx.x; int l = threadIdx.x;   // 64 threads = 1 wave
  unsigned long long vw = (l < NW) ? vwp[n * NW + l] : 0ULL;
  unsigned long long remv = 0ULL, keepw = 0ULL;
  const unsigned long long* sbase = sup + (size_t)n * NPRE * NW;
  unsigned long long r = (l < NPRE) ? sbase[(size_t)l * NW] : 0ULL;  // b=0 diag
  for (int b = 0; b < NW; ++b) {
    // prefetch next diagonal word (overlaps with propagation loads below)
    unsigned long long rn = 0ULL;
    if (b + 1 < NW) {
      int gi = (b + 1) * 64 + l;
      if (gi < NPRE) rn = sbase[(size_t)gi * NW + (b + 1)];
    }
    unsigned long long kept = __shfl(vw & ~remv, b);
    // intra-block sequential resolve (kept/todo are wave-uniform)
    unsigned long long todo = kept;
    while (todo) {
      int i = __builtin_ctzll(todo);
      unsigned long long ri = __shfl(r, i);
      kept &= ~ri;
      todo &= todo - 1;
      todo &= ~ri;
    }
    if (l == b) keepw = kept;
    // propagate suppression of kept candidates to all later column-blocks,
    // 8 independent loads per batch (wave-uniform control flow, no scratch)
    unsigned long long m = kept;
    while (m) {
      int i0 = __builtin_ctzll(m); m &= m - 1;
      int i1 = -1, i2 = -1, i3 = -1, i4 = -1, i5 = -1, i6 = -1, i7 = -1;
      if (m) { i1 = __builtin_ctzll(m); m &= m - 1; }
      if (m) { i2 = __builtin_ctzll(m); m &= m - 1; }
      if (m) { i3 = __builtin_ctzll(m); m &= m - 1; }
      if (m) { i4 = __builtin_ctzll(m); m &= m - 1; }
      if (m) { i5 = __builtin_ctzll(m); m &= m - 1; }
      if (m) { i6 = __builtin_ctzll(m); m &= m - 1; }
      if (m) { i7 = __builtin_ctzll(m); m &= m - 1; }
      if (l < NW) {
        const unsigned long long* rb = sbase + (size_t)(b << 6) * NW + l;
        unsigned long long a0 = rb[(size_t)i0 * NW];
        unsigned long long a1 = (i1 >= 0) ? rb[(size_t)i1 * NW] : 0ULL;
        unsigned long long a2 = (i2 >= 0) ? rb[(size_t)i2 * NW] : 0ULL;
        unsigned long long a3 = (i3 >= 0) ? rb[(size_t)i3 * NW] : 0ULL;
        unsigned long long a4 = (i4 >= 0) ? rb[(size_t)i4 * NW] : 0ULL;
        unsigned long long a5 = (i5 >= 0) ? rb[(size_t)i5 * NW] : 0ULL;
        unsigned long long a6 = (i6 >= 0) ? rb[(size_t)i6 * NW] : 0ULL;
        unsigned long long a7 = (i7 >= 0) ? rb[(size_t)i7 * NW] : 0ULL;
        remv |= (((a0 | a1) | (a2 | a3)) | ((a4 | a5) | (a6 | a7)));
      }
    }
    r = rn;
  }
  unsigned long long keep = keepw;
  int cnt = __popcll(keep);
  int pre = cnt;
#pragma unroll
  for (int d = 1; d < 64; d <<= 1) {
    int tt = __shfl_up(pre, d);
    if (l >= d) pre += tt;
  }
  int nk = __shfl(pre, 63);
  int excl = pre - cnt;
  __shared__ float sbox[NPOST * 4];
  unsigned long long m2 = keep; int rank = excl;
  while (m2) {
    int b = __builtin_ctzll(m2);
    m2 &= m2 - 1;
    if (rank < NPOST) {
      int j = (l << 6) + b;
      const double* bj = bsort + ((size_t)n * NPRE + j) * 4;
      sbox[rank*4]   = (float)bj[0]; sbox[rank*4+1] = (float)bj[1];
      sbox[rank*4+2] = (float)bj[2]; sbox[rank*4+3] = (float)bj[3];
    }
    ++rank;
  }
  __syncthreads();
  if (nk == 0 && l == 0) {
    const double* b0 = bsort + (size_t)n * NPRE * 4;
    sbox[0] = (float)b0[0]; sbox[1] = (float)b0[1];
    sbox[2] = (float)b0[2]; sbox[3] = (float)b0[3];
  }
  __syncthreads();
  int nke = nk > 0 ? nk : 1;
  for (int r2 = l; r2 < NPOST; r2 += 64) {
    int src = r2 < nke ? r2 : r2 % nke;
    float4 b4 = *(float4*)(sbox + src * 4);
    *(float4*)(out + OFF_ROIS + ((size_t)n * NPOST + r2) * 4) = b4;
    out[OFF_IDX + n * NPOST + r2] = (float)n;
  }
}

extern "C" void kernel_launch(void* const* d_in, const int* in_sizes, int n_in,
                              void* d_out, int out_size, void* d_ws, size_t ws_size,
                              hipStream_t stream) {
  const float* X  = (const float*)d_in[0];
  const float* CW = (const float*)d_in[1];
  const float* CB = (const float*)d_in[2];
  const float* SW = (const float*)d_in[3];
  const float* SB = (const float*)d_in[4];
  const float* LW = (const float*)d_in[5];
  const float* LB = (const float*)d_in[6];
  const int*   IH = (const int*)d_in[7];
  const int*   IW = (const int*)d_in[8];
  float* out = (float*)d_out;
  char* ws = (char*)d_ws;

  // ws carve. sup OVERLAYS feat (feat dead after heads_k). Peak: 14,949,504 B.
  float* feat = (float*)(ws + 0);                                  // 11,829,248
  unsigned long long* sup  = (unsigned long long*)(ws + 0);        //  4,512,000 (overlay)
  float* Wt    = (float*)(ws + 11829248);                          //    131,072
  double* fg   = (double*)(ws + 11960320);                         //    415,872
  double* boxes= (double*)(ws + 12376192);                         //  1,663,488
  unsigned long long* keys = (unsigned long long*)(ws + 14039680); //    524,288
  double* bsort= (double*)(ws + 14563968);                         //    384,000
  unsigned long long* vw   = (unsigned long long*)(ws + 14947968); //      1,536

  hipLaunchKernelGGL(wt_k,     dim3(128),        dim3(256),  0, stream, LW, SW, Wt);
  hipLaunchKernelGGL(conv_k,   dim3(38, 8, 4),   dim3(256),  0, stream, X, CW, CB, feat);
  hipLaunchKernelGGL(heads_k,  dim3(361, 4),     dim3(256),  0, stream, feat, Wt, LB, SB, out, fg);
  hipLaunchKernelGGL(decode_k, dim3(256),        dim3(256),  0, stream, out, out, fg, IH, IW, boxes, keys);
  hipLaunchKernelGGL(sortA_k,  dim3(8),          dim3(1024), 0, stream, keys);
  hipLaunchKernelGGL(sortB_k,  dim3(128),        dim3(256),  0, stream, keys);
  hipLaunchKernelGGL(sortC_k,  dim3(8),          dim3(1024), 0, stream, keys);
  hipLaunchKernelGGL(gather_k, dim3(47, 4),      dim3(64),   0, stream, keys, boxes, bsort, vw);
  hipLaunchKernelGGL(iou_k,    dim3((4*NPRE*NW + 255) / 256), dim3(256), 0, stream, bsort, sup);
  hipLaunchKernelGGL(nms_k,    dim3(4),          dim3(64),   0, stream, sup, vw, bsort, out);
}

// Round 11
// 968.607 us; speedup vs baseline: 1.4371x; 1.4371x over previous
//
#include <hip/hip_runtime.h>
#include <cstdint>
#include <cstddef>

#define HW    1444      // 38*38
#define NA    12996     // HW*9
#define NPRE  3000
#define NW    47        // ceil(3000/64)
#define NPOST 300

// d_out section offsets (in floats)
#define OFF_LOCS   0         // 4*12996*4 = 207936
#define OFF_SCORES 207936    // 4*12996*2 = 103968
#define OFF_ROIS   311904    // 1200*4    = 4800
#define OFF_IDX    316704    // 4*300     = 1200
#define OFF_ANCH   317904    // 12996*4   = 51984

#define INVALID_KEY 0xFFF0000000000000ULL

typedef float f32x2 __attribute__((ext_vector_type(2)));
typedef float f32x4 __attribute__((ext_vector_type(4)));

__device__ inline double as_dim(int raw) {
  if (raw > 0 && raw < 1000000) return (double)raw;
  return (double)__int_as_float(raw);
}

// -------- W transpose + keys padding (idle-thread fusion) -------------------
// Wt[c*64 + o], o<36 loc, 36..53 score. Also writes the ~0 keys for the
// padded index range i in [NA,16384) that decode_k used to write.
__global__ __launch_bounds__(256) void wt_k(const float* __restrict__ lw,
                                            const float* __restrict__ sw,
                                            float* __restrict__ Wt,
                                            unsigned long long* __restrict__ keys) {
  int t = blockIdx.x * 256 + threadIdx.x;
  if (t < 4 * (16384 - NA)) {            // 13552 pad keys
    int n2 = t / (16384 - NA), r = t - n2 * (16384 - NA);
    keys[((size_t)n2 << 14) + NA + r] = ~0ULL;
  }
  if (t >= 64 * 512) return;
  int o = t & 63, c = t >> 6;
  float v = 0.f;
  if (o < 36)      v = lw[o * 512 + c];
  else if (o < 54) v = sw[(o - 36) * 512 + c];
  Wt[t] = v;
}

// ------- 3x3 conv: R9 VERBATIM (best measured: 564us, 0 bank conflicts) ----
// R10's per-lane global w gather was uncoalesced (64 cache lines per
// dwordx4) and regressed to 990us -> reverted to the staged-LDS w path.
__global__ __launch_bounds__(256) void conv_k(const float* __restrict__ X,
                                              const float* __restrict__ W,
                                              const float* __restrict__ B,
                                              float* __restrict__ F) {
  __shared__ float Xs[1008];   // A: [4cl][3row][40]=480 | B: [4cl][3row][44]=528
  __shared__ float Wsf[2304];  // [o=64][36] f32, 9216 B, lane-contiguous
  const int tid  = threadIdx.x;
  const int lane = tid & 63;
  const int wv   = tid >> 6;
  const int seg  = wv * 10;        // cols seg..seg+9 (wave 3: 30..37 + 2 dummy)
  const int y  = blockIdx.x;
  const int o0 = blockIdx.y * 64;
  const int n  = blockIdx.z;
  const float* xn = X + ((size_t)n * 512) * HW;

  // ---- staging descriptors (computed once) ----
  int xsrcA[2]; bool xvalA[2]; bool xactA1;
  {
    int e = tid;
    int cl = e / 120, rem = e - cl * 120, row = rem / 40, colA = rem - row * 40;
    int m = colA - 1, iy = y - 1 + row;
    xvalA[0] = (m >= 0 && m < 38 && iy >= 0 && iy < 38);
    xsrcA[0] = xvalA[0] ? (cl * HW + iy * 38 + m) : 0;
  }
  {
    int e = tid + 256; xactA1 = (e < 480);
    int cl = e / 120, rem = e - cl * 120, row = rem / 40, colA = rem - row * 40;
    int m = colA - 1, iy = y - 1 + row;
    xvalA[1] = xactA1 && (m >= 0 && m < 38 && iy >= 0 && iy < 38);
    xsrcA[1] = xvalA[1] ? (cl * HW + iy * 38 + m) : 0;
  }
  int xsrcB[3]; bool xvalB[3]; bool xactB2;
#pragma unroll
  for (int u = 0; u < 3; ++u) {
    int e = tid + u * 256;
    bool act = (e < 528);
    int cl = e / 132, rem = e - cl * 132, row = rem / 44, colB = rem - row * 44;
    int m = colB - 3, iy = y - 1 + row;
    xvalB[u] = act && (m >= 0 && m < 38 && iy >= 0 && iy < 38);
    xsrcB[u] = xvalB[u] ? (cl * HW + iy * 38 + m) : 0;
    if (u == 2) xactB2 = act;
  }
  int wsrc[9];
#pragma unroll
  for (int u = 0; u < 9; ++u) {
    int e = tid + u * 256;           // covers 0..2303 exactly (64 o x 36)
    int ol = e / 36, t36 = e - ol * 36;
    wsrc[u] = (o0 + ol) * 4608 + t36;
  }

  float xrA[2], xrB[3], wr_[9];
#pragma unroll
  for (int u = 0; u < 2; ++u) xrA[u] = xvalA[u] ? xn[xsrcA[u]] : 0.f;
#pragma unroll
  for (int u = 0; u < 3; ++u) xrB[u] = xvalB[u] ? xn[xsrcB[u]] : 0.f;
#pragma unroll
  for (int u = 0; u < 9; ++u) wr_[u] = W[wsrc[u]];

  double acc[10];
#pragma unroll
  for (int p = 0; p < 10; ++p) acc[p] = 0.;
  f32x2 pA[5], pB[5];
  float pc0 = 0.f;

  const int  xb0   = (wv & 1) ? (480 + seg + 2) : seg;
  const int  cstep = (wv & 1) ? 132 : 120;
  const int  kstep = (wv & 1) ? 44 : 40;

#define WQ_ELEM(t) ((t & 3) == 0 ? wq[(t) >> 2].x : (t & 3) == 1 ? wq[(t) >> 2].y : \
                    (t & 3) == 2 ? wq[(t) >> 2].z : wq[(t) >> 2].w)

  for (int cc = 0; cc < 128; ++cc) {
    __syncthreads();
    Xs[tid] = xrA[0];
    if (xactA1) Xs[tid + 256] = xrA[1];
    Xs[480 + tid] = xrB[0];
    Xs[480 + tid + 256] = xrB[1];
    if (xactB2) Xs[480 + tid + 512] = xrB[2];
#pragma unroll
    for (int u = 0; u < 9; ++u) Wsf[tid + u * 256] = wr_[u];
    __syncthreads();
    if (cc < 127) {
      const int cb = (cc + 1) * 4;
#pragma unroll
      for (int u = 0; u < 2; ++u) xrA[u] = xvalA[u] ? xn[cb * HW + xsrcA[u]] : 0.f;
#pragma unroll
      for (int u = 0; u < 3; ++u) xrB[u] = xvalB[u] ? xn[cb * HW + xsrcB[u]] : 0.f;
#pragma unroll
      for (int u = 0; u < 9; ++u) wr_[u] = W[wsrc[u] + (cc + 1) * 36];
    }
    f32x4 wq[9];
    {
      const f32x4* wrow = (const f32x4*)&Wsf[lane * 36];
#pragma unroll
      for (int q = 0; q < 9; ++q) wq[q] = wrow[q];
    }
    if ((cc & 1) == 0) {
#pragma unroll
      for (int a = 0; a < 5; ++a) { pA[a] = (f32x2)(0.f); pB[a] = (f32x2)(0.f); }
      pc0 = 0.f;
    }
#pragma unroll
    for (int cl = 0; cl < 4; ++cl) {
      f32x2 wp[9];
#pragma unroll
      for (int k = 0; k < 9; ++k) {
        float wv0 = WQ_ELEM(cl * 9 + k);
        wp[k][0] = wv0; wp[k][1] = wv0;
      }
#pragma unroll
      for (int ky = 0; ky < 3; ++ky) {
        const float* xrow = &Xs[xb0 + cl * cstep + ky * kstep]; // 16B-aligned
        f32x4 q0 = *(const f32x4*)(xrow);
        f32x4 q1 = *(const f32x4*)(xrow + 4);
        f32x4 q2 = *(const f32x4*)(xrow + 8);
        f32x2 xp[6];
        xp[0] = __builtin_shufflevector(q0, q0, 0, 1);
        xp[1] = __builtin_shufflevector(q0, q0, 2, 3);
        xp[2] = __builtin_shufflevector(q1, q1, 0, 1);
        xp[3] = __builtin_shufflevector(q1, q1, 2, 3);
        xp[4] = __builtin_shufflevector(q2, q2, 0, 1);
        xp[5] = __builtin_shufflevector(q2, q2, 2, 3);
#pragma unroll
        for (int a = 0; a < 5; ++a)
          asm("v_pk_fma_f32 %0, %1, %2, %0"
              : "+v"(pA[a]) : "v"(xp[a]), "v"(wp[ky * 3 + 0]));
        pc0 = fmaf(wp[ky * 3 + 1][0], xp[0][1], pc0);
#pragma unroll
        for (int a = 0; a < 5; ++a)
          asm("v_pk_fma_f32 %0, %1, %2, %0"
              : "+v"(pB[a]) : "v"(xp[a + 1]), "v"(wp[ky * 3 + 1]));
#pragma unroll
        for (int a = 0; a < 5; ++a)
          asm("v_pk_fma_f32 %0, %1, %2, %0"
              : "+v"(pA[a]) : "v"(xp[a + 1]), "v"(wp[ky * 3 + 2]));
      }
    }
    if (cc & 1) {
      acc[0] += (double)(pA[0][0] + pc0);
#pragma unroll
      for (int p = 1; p < 10; ++p) {
        float sa = pA[p >> 1][p & 1];
        float sb = (p & 1) ? pB[(p - 1) >> 1][0] : pB[(p - 2) >> 1][1];
        acc[p] += (double)(sa + sb);
      }
    }
  }
  double bb = (double)B[o0 + lane];
  float* fp = F + ((size_t)(n * 512 + o0 + lane)) * HW + y * 38;
#pragma unroll
  for (int p = 0; p < 10; ++p) {
    int col = seg + p;
    if (col < 38) fp[col] = (float)fmax(acc[p] + bb, 0.0);
  }
}

// ------- 1x1 heads + softmax + FUSED decode/keys (R11) ----------------------
// Decode reads the SAME fp32-rounded loc values it previously read from
// d_out (staged in sloc as (float)acc) and the same fp64 fg computed here
// -> boxes/keys BIT-IDENTICAL to the old heads_k->decode_k pipeline.
__global__ __launch_bounds__(256) void heads_k(const float* __restrict__ F,
                                               const float* __restrict__ Wt,
                                               const float* __restrict__ lb,
                                               const float* __restrict__ sb,
                                               const int* __restrict__ ihp,
                                               const int* __restrict__ iwp,
                                               float* __restrict__ out,
                                               double* __restrict__ boxes,
                                               unsigned long long* __restrict__ keys) {
  __shared__ float sf[512 * 4];
  __shared__ double ssc[4][18];
  __shared__ float sloc[4][36];
  int n = blockIdx.y;
  int p0 = blockIdx.x * 4;
  int tid = threadIdx.x;
  const float* fn = F + ((size_t)n * 512) * HW;
  for (int e = tid; e < 2048; e += 256) {
    int c = e >> 2, pl = e & 3;
    sf[e] = fn[c * HW + p0 + pl];
  }
  __syncthreads();
  int pl = tid & 3, o = tid >> 2;
  double acc = 0.;
  if (o < 54) {
    for (int c = 0; c < 512; ++c)
      acc = fma((double)Wt[(c << 6) | o], (double)sf[(c << 2) | pl], acc);
  }
  int p = p0 + pl;
  if (o < 36) {
    acc += (double)lb[o];
    float v = (float)acc;
    out[OFF_LOCS + ((size_t)n * NA + (size_t)p * 9 + (o >> 2)) * 4 + (o & 3)] = v;
    sloc[pl][o] = v;
  } else if (o < 54) {
    int oo = o - 36;
    acc += (double)sb[oo];
    out[OFF_SCORES + ((size_t)n * NA + (size_t)p * 9 + (oo >> 1)) * 2 + (oo & 1)] = (float)acc;
    ssc[pl][oo] = acc;
  }
  __syncthreads();
  if (tid < 36) {
    int pl2 = tid / 9, a = tid - pl2 * 9;
    // fp64 softmax (identical to old fg computation)
    double s0 = ssc[pl2][a * 2], s1 = ssc[pl2][a * 2 + 1];
    double mx = fmax(s0, s1);
    double e0 = exp(s0 - mx), e1 = exp(s1 - mx);
    double sc = e1 / (e0 + e1);
    // fused decode (verbatim math from old decode_k)
    int pp = p0 + pl2;
    int i = pp * 9 + a;
    int ri = a / 3, si = a - ri * 3;
    double sr  = (ri == 0) ? 0.7071067811865476 : (ri == 1 ? 1.0 : 1.4142135623730951);
    double sri = (ri == 0) ? 1.4142135623730951 : (ri == 1 ? 1.0 : 0.7071067811865476);
    double hs = (double)(128 << si) * sr;
    double wd = (double)(128 << si) * sri;
    int py = pp / 38, px = pp - py * 38;
    float sx = (float)(px * 16), sy = (float)(py * 16);
    float fx1 = (float)(8.0 - 0.5 * wd), fy1 = (float)(8.0 - 0.5 * hs);
    float fx2 = (float)(8.0 + 0.5 * wd), fy2 = (float)(8.0 + 0.5 * hs);
    float ax1f = sx + fx1, ay1f = sy + fy1, ax2f = sx + fx2, ay2f = sy + fy2;
    if (n == 0) {
      float* ap = out + OFF_ANCH + (size_t)i * 4;
      ap[0] = ax1f; ap[1] = ay1f; ap[2] = ax2f; ap[3] = ay2f;
    }
    double ax1 = ax1f, ay1 = ay1f, ax2 = ax2f, ay2 = ay2f;
    double aw = ax2 - ax1, ah = ay2 - ay1;
    double acx = ax1 + 0.5 * aw, acy = ay1 + 0.5 * ah;
    double l0 = (double)sloc[pl2][a * 4 + 0], l1 = (double)sloc[pl2][a * 4 + 1];
    double l2 = (double)sloc[pl2][a * 4 + 2], l3 = (double)sloc[pl2][a * 4 + 3];
    double cx = l0 * aw + acx, cy = l1 * ah + acy;
    double bw = aw * exp(l2), bh = ah * exp(l3);
    double iwf = as_dim(iwp[0]), ihf = as_dim(ihp[0]);
    double x1 = fmin(fmax(cx - 0.5 * bw, 0.0), iwf);
    double y1 = fmin(fmax(cy - 0.5 * bh, 0.0), ihf);
    double x2 = fmin(fmax(cx + 0.5 * bw, 0.0), iwf);
    double y2 = fmin(fmax(cy + 0.5 * bh, 0.0), ihf);
    bool valid = ((x2 - x1) >= 16.0) && ((y2 - y1) >= 16.0);
    double* bp = boxes + ((size_t)n * NA + i) * 4;
    bp[0] = x1; bp[1] = y1; bp[2] = x2; bp[3] = y2;
    unsigned long long u = (unsigned long long)__double_as_longlong(sc);
    u = (u >> 63) ? ~u : (u | 0x8000000000000000ULL);  // ascending-sortable
    unsigned long long inv = ~u;                       // descending
    if (!valid) inv = INVALID_KEY;
    keys[((size_t)n << 14) + i] = (inv & ~0x3FFFULL) | (unsigned long long)i;
  }
}

// ---- sort phase A: per-8192-half in-LDS bitonic sort (half0 asc, half1 desc)
__global__ __launch_bounds__(1024) void sortA_k(unsigned long long* __restrict__ keys) {
  __shared__ unsigned long long s[8192];   // 64 KB
  const int half = blockIdx.x & 1;
  unsigned long long* g = keys + (((size_t)(blockIdx.x >> 1)) << 14) + ((size_t)half << 13);
  const int tid = threadIdx.x;
  for (int i = tid; i < 8192; i += 1024) s[i] = g[i];
  for (int size = 2; size <= 8192; size <<= 1) {
    for (int stride = size >> 1; stride > 0; stride >>= 1) {
      __syncthreads();
      for (int u = tid; u < 4096; u += 1024) {
        int lo = u & (stride - 1);
        int i1 = ((u - lo) << 1) | lo;
        int i2 = i1 + stride;
        bool up = (i1 & size) == 0;
        if (half) up = !up;   // upper half sorts descending
        unsigned long long a = s[i1], b = s[i2];
        if ((a > b) == up) { s[i1] = b; s[i2] = a; }
      }
    }
  }
  __syncthreads();
  for (int i = tid; i < 8192; i += 1024) g[i] = s[i];
}

// ---- sort final merge + gather, FUSED (R11) --------------------------------
// Only half0 of the final 16384-merge is ever consumed (top-3000 < 8192), so:
// s[i] = min(g[i], g[i+8192])  (the old sortB restricted to half0), bitonic
// merge ascending in LDS (old sortC half0), then gather bsort/vw straight
// from LDS (old gather_k). keys are never written -> no inter-block race.
// One 4-block kernel replaces three kernels; selection results identical.
__global__ __launch_bounds__(1024) void sortCG_k(const unsigned long long* __restrict__ keys,
                                                 const double* __restrict__ boxes,
                                                 double* __restrict__ bsort,
                                                 unsigned long long* __restrict__ vw) {
  __shared__ unsigned long long s[8192];   // 64 KB
  const int n = blockIdx.x;
  const unsigned long long* g = keys + ((size_t)n << 14);
  const int tid = threadIdx.x;
  for (int i = tid; i < 8192; i += 1024) {
    unsigned long long a = g[i], b = g[i + 8192];
    s[i] = a < b ? a : b;
  }
  for (int stride = 4096; stride > 0; stride >>= 1) {
    __syncthreads();
    for (int u = tid; u < 4096; u += 1024) {
      int lo = u & (stride - 1);
      int i1 = ((u - lo) << 1) | lo;
      int i2 = i1 + stride;
      unsigned long long a = s[i1], b = s[i2];
      if (a > b) { s[i1] = b; s[i2] = a; }
    }
  }
  __syncthreads();
  const int lane = tid & 63;
#pragma unroll
  for (int r3 = 0; r3 < 3; ++r3) {
    int r = r3 * 1024 + tid;
    bool valid = false;
    if (r < NPRE) {
      unsigned long long kk = s[r];
      valid = kk < INVALID_KEY;
      unsigned idx = (unsigned)(kk & 0x3FFFULL);
      const double* bp = boxes + ((size_t)n * NA + idx) * 4;
      double* dp = bsort + ((size_t)n * NPRE + r) * 4;
      dp[0] = bp[0]; dp[1] = bp[1]; dp[2] = bp[2]; dp[3] = bp[3];
    }
    unsigned long long mask = __ballot(valid);
    int w = r >> 6;
    if (lane == 0 && w < NW) vw[n * NW + w] = mask;
  }
}

// ------- suppression matrix (fp64 IoU): bit j set iff j>i && iou>0.7 --------
// R11: divide removed — iou>0.7 <=> (uni>0 && inter > 0.7*uni); flips only
// within 1 ulp fp64 of the threshold, far inside the tolerated fp32 noise.
__global__ __launch_bounds__(256) void iou_k(const double* __restrict__ bsort,
                                             unsigned long long* __restrict__ sup) {
  int t = blockIdx.x * 256 + threadIdx.x;
  if (t >= 4 * NPRE * NW) return;
  int w = t % NW; int rest = t / NW; int i = rest % NPRE; int n = rest / NPRE;
  const double* bb = bsort + (size_t)n * NPRE * 4;
  double bix1 = bb[(size_t)i*4], biy1 = bb[(size_t)i*4+1];
  double bix2 = bb[(size_t)i*4+2], biy2 = bb[(size_t)i*4+3];
  double ai = (bix2 - bix1) * (biy2 - biy1);
  unsigned long long word = 0ULL;
  int j0 = w << 6;
  if (j0 + 63 > i) {
    int lmax = NPRE - j0; if (lmax > 64) lmax = 64;
    for (int l = 0; l < lmax; ++l) {
      int j = j0 + l;
      if (j <= i) continue;
      const double* bj = bb + (size_t)j * 4;
      double aj = (bj[2] - bj[0]) * (bj[3] - bj[1]);
      double xx1 = fmax(bix1, bj[0]), yy1 = fmax(biy1, bj[1]);
      double xx2 = fmin(bix2, bj[2]), yy2 = fmin(biy2, bj[3]);
      double inter = fmax(xx2 - xx1, 0.0) * fmax(yy2 - yy1, 0.0);
      double uni = ai + aj - inter;
      bool supb = (uni > 0.0) && (inter > 0.7 * uni);
      word |= (unsigned long long)supb << l;
    }
  }
  sup[((size_t)n * NPRE + i) * NW + w] = word;
}

// ------- NMS: block-64 mask propagation (1 wave/batch) + emit rois ----------
__global__ void nms_k(const unsigned long long* __restrict__ sup,
                      const unsigned long long* __restrict__ vwp,
                      const double* __restrict__ bsort,
                      float* __restrict__ out) {
  int n = blockIdx.x; int l = threadIdx.x;   // 64 threads = 1 wave
  unsigned long long vw = (l < NW) ? vwp[n * NW + l] : 0ULL;
  unsigned long long remv = 0ULL, keepw = 0ULL;
  const unsigned long long* sbase = sup + (size_t)n * NPRE * NW;
  unsigned long long r = (l < NPRE) ? sbase[(size_t)l * NW] : 0ULL;  // b=0 diag
  for (int b = 0; b < NW; ++b) {
    unsigned long long rn = 0ULL;
    if (b + 1 < NW) {
      int gi = (b + 1) * 64 + l;
      if (gi < NPRE) rn = sbase[(size_t)gi * NW + (b + 1)];
    }
    unsigned long long kept = __shfl(vw & ~remv, b);
    unsigned long long todo = kept;
    while (todo) {
      int i = __builtin_ctzll(todo);
      unsigned long long ri = __shfl(r, i);
      kept &= ~ri;
      todo &= todo - 1;
      todo &= ~ri;
    }
    if (l == b) keepw = kept;
    unsigned long long m = kept;
    while (m) {
      int i0 = __builtin_ctzll(m); m &= m - 1;
      int i1 = -1, i2 = -1, i3 = -1, i4 = -1, i5 = -1, i6 = -1, i7 = -1;
      if (m) { i1 = __builtin_ctzll(m); m &= m - 1; }
      if (m) { i2 = __builtin_ctzll(m); m &= m - 1; }
      if (m) { i3 = __builtin_ctzll(m); m &= m - 1; }
      if (m) { i4 = __builtin_ctzll(m); m &= m - 1; }
      if (m) { i5 = __builtin_ctzll(m); m &= m - 1; }
      if (m) { i6 = __builtin_ctzll(m); m &= m - 1; }
      if (m) { i7 = __builtin_ctzll(m); m &= m - 1; }
      if (l < NW) {
        const unsigned long long* rb = sbase + (size_t)(b << 6) * NW + l;
        unsigned long long a0 = rb[(size_t)i0 * NW];
        unsigned long long a1 = (i1 >= 0) ? rb[(size_t)i1 * NW] : 0ULL;
        unsigned long long a2 = (i2 >= 0) ? rb[(size_t)i2 * NW] : 0ULL;
        unsigned long long a3 = (i3 >= 0) ? rb[(size_t)i3 * NW] : 0ULL;
        unsigned long long a4 = (i4 >= 0) ? rb[(size_t)i4 * NW] : 0ULL;
        unsigned long long a5 = (i5 >= 0) ? rb[(size_t)i5 * NW] : 0ULL;
        unsigned long long a6 = (i6 >= 0) ? rb[(size_t)i6 * NW] : 0ULL;
        unsigned long long a7 = (i7 >= 0) ? rb[(size_t)i7 * NW] : 0ULL;
        remv |= (((a0 | a1) | (a2 | a3)) | ((a4 | a5) | (a6 | a7)));
      }
    }
    r = rn;
  }
  unsigned long long keep = keepw;
  int cnt = __popcll(keep);
  int pre = cnt;
#pragma unroll
  for (int d = 1; d < 64; d <<= 1) {
    int tt = __shfl_up(pre, d);
    if (l >= d) pre += tt;
  }
  int nk = __shfl(pre, 63);
  int excl = pre - cnt;
  __shared__ float sbox[NPOST * 4];
  unsigned long long m2 = keep; int rank = excl;
  while (m2) {
    int b = __builtin_ctzll(m2);
    m2 &= m2 - 1;
    if (rank < NPOST) {
      int j = (l << 6) + b;
      const double* bj = bsort + ((size_t)n * NPRE + j) * 4;
      sbox[rank*4]   = (float)bj[0]; sbox[rank*4+1] = (float)bj[1];
      sbox[rank*4+2] = (float)bj[2]; sbox[rank*4+3] = (float)bj[3];
    }
    ++rank;
  }
  __syncthreads();
  if (nk == 0 && l == 0) {
    const double* b0 = bsort + (size_t)n * NPRE * 4;
    sbox[0] = (float)b0[0]; sbox[1] = (float)b0[1];
    sbox[2] = (float)b0[2]; sbox[3] = (float)b0[3];
  }
  __syncthreads();
  int nke = nk > 0 ? nk : 1;
  for (int r2 = l; r2 < NPOST; r2 += 64) {
    int src = r2 < nke ? r2 : r2 % nke;
    float4 b4 = *(float4*)(sbox + src * 4);
    *(float4*)(out + OFF_ROIS + ((size_t)n * NPOST + r2) * 4) = b4;
    out[OFF_IDX + n * NPOST + r2] = (float)n;
  }
}

extern "C" void kernel_launch(void* const* d_in, const int* in_sizes, int n_in,
                              void* d_out, int out_size, void* d_ws, size_t ws_size,
                              hipStream_t stream) {
  const float* X  = (const float*)d_in[0];
  const float* CW = (const float*)d_in[1];
  const float* CB = (const float*)d_in[2];
  const float* SW = (const float*)d_in[3];
  const float* SB = (const float*)d_in[4];
  const float* LW = (const float*)d_in[5];
  const float* LB = (const float*)d_in[6];
  const int*   IH = (const int*)d_in[7];
  const int*   IW = (const int*)d_in[8];
  float* out = (float*)d_out;
  char* ws = (char*)d_ws;

  // ws carve. sup OVERLAYS feat (feat dead after heads_k). Peak: 14,949,504 B.
  // (fg region retained in the map but unused since decode fused into heads.)
  float* feat = (float*)(ws + 0);                                  // 11,829,248
  unsigned long long* sup  = (unsigned long long*)(ws + 0);        //  4,512,000 (overlay)
  float* Wt    = (float*)(ws + 11829248);                          //    131,072
  double* boxes= (double*)(ws + 12376192);                         //  1,663,488
  unsigned long long* keys = (unsigned long long*)(ws + 14039680); //    524,288
  double* bsort= (double*)(ws + 14563968);                         //    384,000
  unsigned long long* vw   = (unsigned long long*)(ws + 14947968); //      1,536

  hipLaunchKernelGGL(wt_k,    dim3(128),      dim3(256),  0, stream, LW, SW, Wt, keys);
  hipLaunchKernelGGL(conv_k,  dim3(38, 8, 4), dim3(256),  0, stream, X, CW, CB, feat);
  hipLaunchKernelGGL(heads_k, dim3(361, 4),   dim3(256),  0, stream,
                     feat, Wt, LB, SB, IH, IW, out, boxes, keys);
  hipLaunchKernelGGL(sortA_k, dim3(8),        dim3(1024), 0, stream, keys);
  hipLaunchKernelGGL(sortCG_k,dim3(4),        dim3(1024), 0, stream, keys, boxes, bsort, vw);
  hipLaunchKernelGGL(iou_k,   dim3((4*NPRE*NW + 255) / 256), dim3(256), 0, stream, bsort, sup);
  hipLaunchKernelGGL(nms_k,   dim3(4),        dim3(64),   0, stream, sup, vw, bsort, out);
}